// Round 8
// baseline (130.299 us; speedup 1.0000x reference)
//
#include <hip/hip_runtime.h>
#include <hip/hip_bf16.h>

#define BN 8192
#define DIM 512
#define NB  64            // BN / 128 block-rows
#define EPSF 1e-8f

using v8i   = __attribute__((ext_vector_type(8))) int;
using v4i   = __attribute__((ext_vector_type(4))) int;
using f32x4 = __attribute__((ext_vector_type(4))) float;

// Async global->LDS, 16 B per lane, dest = uniform base + lane*16.
__device__ inline void async_copy16(const void* g, void* l) {
    __builtin_amdgcn_global_load_lds(
        (const __attribute__((address_space(1))) void*)g,
        (__attribute__((address_space(3))) void*)l,
        16, 0, 0);
}

// One wave per row: L2-normalize, scale by 4, convert to fp8 e4m3.
// (x4 pre-scale keeps values in e4m3 normal range; S = acc/16 in epilogue.)
// Also zeroes out[0] (replaces a memset dispatch).
__global__ __launch_bounds__(256) void normalize_kernel(
        const float* __restrict__ emb, unsigned char* __restrict__ E,
        float* __restrict__ out) {
    if (blockIdx.x == 0 && threadIdx.x == 0) out[0] = 0.f;
    int wave = threadIdx.x >> 6;
    int lane = threadIdx.x & 63;
    int row  = blockIdx.x * 4 + wave;
    const float4* src = (const float4*)(emb + (size_t)row * DIM);
    float4 a = src[lane];
    float4 b = src[lane + 64];
    float ss = a.x*a.x + a.y*a.y + a.z*a.z + a.w*a.w
             + b.x*b.x + b.y*b.y + b.z*b.z + b.w*b.w;
    #pragma unroll
    for (int m = 1; m < 64; m <<= 1) ss += __shfl_xor(ss, m, 64);
    float s4 = 4.0f / fmaxf(sqrtf(ss), 1e-12f);
    int pa = __builtin_amdgcn_cvt_pk_fp8_f32(a.x*s4, a.y*s4, 0, false);
    pa     = __builtin_amdgcn_cvt_pk_fp8_f32(a.z*s4, a.w*s4, pa, true);
    int pb = __builtin_amdgcn_cvt_pk_fp8_f32(b.x*s4, b.y*s4, 0, false);
    pb     = __builtin_amdgcn_cvt_pk_fp8_f32(b.z*s4, b.w*s4, pb, true);
    unsigned char* rowp = E + (size_t)row * DIM;
    ((unsigned*)rowp)[lane]         = (unsigned)pa;
    ((unsigned*)(rowp + 256))[lane] = (unsigned)pb;
}

// Upper-triangle 128x128 tiles, 1D grid (2080), triangular decode.
// A-slab (128x512 fp8 = 64 KB) resident in LDS, staged once (one barrier).
// B fragments stream directly global->VGPR from the L2-resident E with an
// EXPLICIT register double-buffer: bf[(k+1)&1] loads issue BEFORE k's MFMA
// block, so L2 latency (~200-400 cyc) hides behind MFMA+ds_read (AITER-style
// pipelining -- expressible here because the k-loop has zero barriers).
// A-slab XOR swizzle: LDS chunk p of row r holds global chunk p ^ (r&7).
// Epilogue: LDS-buffer reduction reusing the As memory.
__global__ __launch_bounds__(256) void gemm_epi_kernel(
        const unsigned char* __restrict__ E, const int* __restrict__ labels,
        float* __restrict__ P, float* __restrict__ N) {
    int t  = blockIdx.x;
    int bi = (int)(64.5f - sqrtf(64.5f * 64.5f - 2.0f * (float)t));
    while (64 * (bi + 1) - ((bi + 1) * bi) / 2 <= t) ++bi;
    while (64 * bi - (bi * (bi - 1)) / 2 > t) --bi;
    int bj = bi + (t - (64 * bi - (bi * (bi - 1)) / 2));
    const bool diag = (bi == bj);

    __shared__ __attribute__((aligned(16))) unsigned char As[128 * DIM]; // 64 KB
    __shared__ int labI[128];
    __shared__ int labJ[128];

    const int tid  = threadIdx.x;
    const int i0   = bi * 128;
    const int j0   = bj * 128;
    const int wave = tid >> 6;
    const int lane = tid & 63;
    const int quad = lane >> 4;    // 0..3
    const int lrow = lane & 15;    // 0..15
    const int i_w  = (wave >> 1) * 64;
    const int j_w  = (wave & 1) * 64;

    if (tid < 128)       labI[tid]       = labels[i0 + tid];
    else                 labJ[tid - 128] = labels[j0 + tid - 128];

    f32x4 acc[4][4];
    #pragma unroll
    for (int a = 0; a < 4; ++a)
        #pragma unroll
        for (int b = 0; b < 4; ++b)
            acc[a][b] = (f32x4){0.f, 0.f, 0.f, 0.f};

    // Stage full A slab: wave w covers rows [w*32, w*32+32), 16 instrs x 1 KB
    // (2 rows each). Lane l: row = base + (l>>5), LDS chunk p = l&31 holds
    // global chunk p ^ (row&7).
    {
        const int ck  = lane & 31;
        const int lr2 = lane >> 5;
        #pragma unroll
        for (int h = 0; h < 16; ++h) {
            int base = wave * 32 + h * 2;
            int rowg = base + lr2;
            int g    = ck ^ (rowg & 7);
            async_copy16(E + (size_t)(i0 + rowg) * DIM + g * 16,
                         As + (size_t)base * DIM);
        }
    }

    // Per-tj B base pointers: k advances by 128 B -> 13-bit immediate offsets.
    const v4i* bptr[4];
    #pragma unroll
    for (int tj = 0; tj < 4; ++tj)
        bptr[tj] = (const v4i*)(E +
            (size_t)(j0 + j_w + tj * 16 + lrow) * DIM + quad * 32);

    // Prefetch B for k=0 (overlaps the staging drain below).
    v8i bf[2][4];
    #pragma unroll
    for (int tj = 0; tj < 4; ++tj) {
        ((v4i*)&bf[0][tj])[0] = bptr[tj][0];
        ((v4i*)&bf[0][tj])[1] = bptr[tj][1];
    }

    __syncthreads();      // vmcnt drain: As + labels ready. ONLY k-loop barrier.

    #pragma unroll
    for (int k = 0; k < 4; ++k) {
        const int cur = k & 1, nxt = cur ^ 1;
        v8i af[4];
        #pragma unroll
        for (int ti = 0; ti < 4; ++ti) {
            int r  = i_w + ti * 16 + lrow;
            const v4i* rp = (const v4i*)(As + (size_t)r * DIM);
            int sw = r & 7;
            ((v4i*)&af[ti])[0] = rp[(k * 8 + quad * 2) ^ sw];
            ((v4i*)&af[ti])[1] = rp[(k * 8 + quad * 2 + 1) ^ sw];
        }
        if (k < 3) {               // issue k+1 B loads BEFORE k's MFMAs
            #pragma unroll
            for (int tj = 0; tj < 4; ++tj) {
                ((v4i*)&bf[nxt][tj])[0] = bptr[tj][(k + 1) * 8];
                ((v4i*)&bf[nxt][tj])[1] = bptr[tj][(k + 1) * 8 + 1];
            }
        }
        #pragma unroll
        for (int ti = 0; ti < 4; ++ti)
            #pragma unroll
            for (int tj = 0; tj < 4; ++tj)
                acc[ti][tj] = __builtin_amdgcn_mfma_scale_f32_16x16x128_f8f6f4(
                                  af[ti], bf[cur][tj], acc[ti][tj],
                                  0, 0,                 // fp8 e4m3 / e4m3
                                  0, 0x7F7F7F7F,        // A scale = 1.0
                                  0, 0x7F7F7F7F);       // B scale = 1.0
    }
    __syncthreads();      // all ds_reads of As done -> reuse as reduction bufs

    // Reuse As memory: rowBuf [256][18] float2 (36.9 KB), colBuf [256][6]
    // float2 (12.3 KB). Variant index: rowBuf v = j_w>>6, colBuf v = i_w>>6.
    float2* rowBuf = (float2*)As;
    float2* colBuf = (float2*)(As + 256 * 18 * 8);
    const int vR = (j_w >> 6);
    const int vC = (i_w >> 6);

    float psC[4] = {0.f, 0.f, 0.f, 0.f};
    float nsC[4] = {0.f, 0.f, 0.f, 0.f};
    #pragma unroll
    for (int ti = 0; ti < 4; ++ti) {
        #pragma unroll
        for (int reg = 0; reg < 4; ++reg) {
            int irow = i_w + ti * 16 + quad * 4 + reg;
            int li   = labI[irow];
            int gi   = i0 + irow;
            float ps = 0.f, ns = 0.f;
            #pragma unroll
            for (int tj = 0; tj < 4; ++tj) {
                int jcol = j_w + tj * 16 + lrow;
                int lj   = labJ[jcol];
                int gj   = j0 + jcol;
                float w  = __expf(fmaf(acc[ti][tj][reg], 0.0625f, -1.0f));
                bool same = (li == lj);
                float wp = (same && (gi != gj)) ? w : 0.f;
                float wn = same ? 0.f : w;
                ps += wp;  ns += wn;
                psC[tj] += wp;  nsC[tj] += wn;
            }
            rowBuf[(size_t)(vR * 128 + irow) * 18 + lrow] = (float2){ps, ns};
        }
    }
    #pragma unroll
    for (int tj = 0; tj < 4; ++tj) {
        int jcol = j_w + tj * 16 + lrow;
        colBuf[(size_t)(vC * 128 + jcol) * 6 + quad] = (float2){psC[tj], nsC[tj]};
    }
    __syncthreads();

    if (tid < 128) {
        const float2* a = rowBuf + (size_t)tid * 18;
        const float2* b = rowBuf + (size_t)(128 + tid) * 18;
        float sp = 0.f, sn = 0.f;
        #pragma unroll
        for (int u = 0; u < 16; ++u) {
            sp += a[u].x + b[u].x;
            sn += a[u].y + b[u].y;
        }
        P[(size_t)bj * BN + i0 + tid] = sp;
        N[(size_t)bj * BN + i0 + tid] = sn;
    } else if (!diag) {
        int c = tid - 128;
        const float2* a = colBuf + (size_t)c * 6;
        const float2* b = colBuf + (size_t)(128 + c) * 6;
        float sp = 0.f, sn = 0.f;
        #pragma unroll
        for (int u = 0; u < 4; ++u) {
            sp += a[u].x + b[u].x;
            sn += a[u].y + b[u].y;
        }
        P[(size_t)bi * BN + j0 + c] = sp;
        N[(size_t)bi * BN + j0 + c] = sn;
    }
}

// Fused tail: 64 blocks x 128 threads. Per-block LDS histogram, per-row
// partial reduce + loss, one atomicAdd of the pre-scaled block sum into
// out[0] (zeroed by normalize_kernel).
__global__ __launch_bounds__(128) void reduce_finalize_kernel(
        const int* __restrict__ labels, const float* __restrict__ P,
        const float* __restrict__ N, float* __restrict__ out) {
    __shared__ int cnt[128];
    __shared__ float wsum[2];
    int tid = threadIdx.x;
    cnt[tid] = 0;
    __syncthreads();
    for (int i = tid; i < BN; i += 128) atomicAdd(&cnt[labels[i]], 1);
    __syncthreads();

    int i = blockIdx.x * 128 + tid;
    float p = 0.f, n = 0.f;
    #pragma unroll 8
    for (int c = 0; c < NB; ++c) {
        p += P[(size_t)c * BN + i];
        n += N[(size_t)c * BN + i];
    }
    int   c  = cnt[labels[i]];
    float pc = (float)(c - 1);
    float nc = (float)(BN - c);
    float pm = p / fmaxf(pc, 1.0f);
    float nm = n / fmaxf(nc, 1.0f);
    float v  = ((c - 1 > 0) && (BN - c > 0))
                   ? -logf(pm / (pm + nm + EPSF)) : 0.0f;
    v *= (1.0f / (float)BN);

    #pragma unroll
    for (int m = 1; m < 64; m <<= 1) v += __shfl_xor(v, m, 64);
    if ((tid & 63) == 0) wsum[tid >> 6] = v;
    __syncthreads();
    if (tid == 0) atomicAdd(out, wsum[0] + wsum[1]);
}

extern "C" void kernel_launch(void* const* d_in, const int* in_sizes, int n_in,
                              void* d_out, int out_size, void* d_ws, size_t ws_size,
                              hipStream_t stream) {
    const float* emb   = (const float*)d_in[0];
    const int* labels  = (const int*)d_in[1];
    float* out         = (float*)d_out;

    // ws layout: E (8 MB reserved; fp8 uses 4) | P (2 MB) | N (2 MB)
    unsigned char* E   = (unsigned char*)d_ws;
    float* P           = (float*)((char*)d_ws + (size_t)BN * DIM * 2);
    float* N           = P + (size_t)NB * BN;

    normalize_kernel<<<BN / 4, 256, 0, stream>>>(emb, E, out);
    gemm_epi_kernel<<<NB * (NB + 1) / 2, 256, 0, stream>>>(E, labels, P, N);
    reduce_finalize_kernel<<<NB, 128, 0, stream>>>(labels, P, N, out);
}

// Round 11
// 124.560 us; speedup vs baseline: 1.0461x; 1.0461x over previous
//
#include <hip/hip_runtime.h>
#include <hip/hip_bf16.h>

#define BN 8192
#define DIM 512
#define NB  64            // BN / 128 block-rows
#define NTILES 2080       // NB*(NB+1)/2 upper-triangle tiles
#define EPSF 1e-8f

using v8i   = __attribute__((ext_vector_type(8))) int;
using v4i   = __attribute__((ext_vector_type(4))) int;
using f32x4 = __attribute__((ext_vector_type(4))) float;

// Async global->LDS, 16 B per lane, dest = uniform base + lane*16.
__device__ __forceinline__ void async_copy16(const void* g, void* l) {
    __builtin_amdgcn_global_load_lds(
        (const __attribute__((address_space(1))) void*)g,
        (__attribute__((address_space(3))) void*)l,
        16, 0, 0);
}

// One wave per row: L2-normalize, x4 pre-scale, fp8 e4m3; out[0] zeroed by
// block 0 (replaces a memset dispatch).
__global__ __launch_bounds__(256) void normalize_kernel(
        const float* __restrict__ emb, unsigned char* __restrict__ E,
        float* __restrict__ out) {
    if (blockIdx.x == 0 && threadIdx.x == 0) out[0] = 0.f;
    int lane = threadIdx.x & 63;
    int row  = blockIdx.x * 4 + (threadIdx.x >> 6);
    const float4* src = (const float4*)(emb + (size_t)row * DIM);
    float4 a = src[lane];
    float4 b = src[lane + 64];
    float ss = a.x*a.x + a.y*a.y + a.z*a.z + a.w*a.w
             + b.x*b.x + b.y*b.y + b.z*b.z + b.w*b.w;
    #pragma unroll
    for (int m = 1; m < 64; m <<= 1) ss += __shfl_xor(ss, m, 64);
    float s4 = 4.0f / fmaxf(sqrtf(ss), 1e-12f);
    int pa = __builtin_amdgcn_cvt_pk_fp8_f32(a.x*s4, a.y*s4, 0, false);
    pa     = __builtin_amdgcn_cvt_pk_fp8_f32(a.z*s4, a.w*s4, pa, true);
    int pb = __builtin_amdgcn_cvt_pk_fp8_f32(b.x*s4, b.y*s4, 0, false);
    pb     = __builtin_amdgcn_cvt_pk_fp8_f32(b.z*s4, b.w*s4, pb, true);
    unsigned char* rowp = E + (size_t)row * DIM;
    ((unsigned*)rowp)[lane]         = (unsigned)pa;
    ((unsigned*)(rowp + 256))[lane] = (unsigned)pb;
}

// Upper-triangle 128x128 tiles, 1D grid (2080), triangular decode.
// fp8 MX MFMA 16x16x128. A-slab in LDS as two BK=256 chunks (32 KB,
// single-buffered) -> total LDS ~46 KB -> 3 blocks/CU co-resident (vs 2 at
// R7's 64 KB), +50% waves to hide VMEM/DS latency. B fragments stream
// directly global->VGPR (E is L2-resident) with a register double-buffer.
// A-slab XOR swizzle: LDS 16B-chunk p of row r holds global chunk p^(r&7).
// Epilogue: exp/mask sums via LDS buffers overlaid on the A-slab memory.
__global__ __launch_bounds__(256) void gemm_epi_kernel(
        const unsigned char* __restrict__ E, const int* __restrict__ labels,
        float* __restrict__ P, float* __restrict__ N) {
    // smem: As chunk (32 KB) overlaid with rowBuf [2][128][17]f2 (34816 B)
    // + colBuf [2][128][5]f2 (10240 B) = 45056 B.
    __shared__ __attribute__((aligned(16))) unsigned char smem[45056];
    __shared__ int labI[128];
    __shared__ int labJ[128];

    int t  = blockIdx.x;
    int bi = (int)(64.5f - sqrtf(64.5f * 64.5f - 2.0f * (float)t));
    while (64 * (bi + 1) - ((bi + 1) * bi) / 2 <= t) ++bi;
    while (64 * bi - (bi * (bi - 1)) / 2 > t) --bi;
    int bj = bi + (t - (64 * bi - (bi * (bi - 1)) / 2));
    const bool diag = (bi == bj);
    const int i0 = bi * 128;
    const int j0 = bj * 128;

    const int tid  = threadIdx.x;
    const int wave = tid >> 6;
    const int lane = tid & 63;
    const int quad = lane >> 4;
    const int lrow = lane & 15;
    const int i_w  = (wave >> 1) * 64;
    const int j_w  = (wave & 1) * 64;

    if (tid < 128)       labI[tid]       = labels[i0 + tid];
    else                 labJ[tid - 128] = labels[j0 + tid - 128];

    unsigned char* As = smem;
    float2* rowBuf = (float2*)smem;               // [2][128][17]
    float2* colBuf = (float2*)(smem + 34816);     // [2][128][5]
    const int vR = wave & 1;
    const int vC = wave >> 1;

    f32x4 acc[4][4];
    #pragma unroll
    for (int a = 0; a < 4; ++a)
        #pragma unroll
        for (int b = 0; b < 4; ++b)
            acc[a][b] = (f32x4){0.f, 0.f, 0.f, 0.f};

    const v4i* bptr[4];
    #pragma unroll
    for (int tj = 0; tj < 4; ++tj)
        bptr[tj] = (const v4i*)(E +
            (size_t)(j0 + j_w + tj * 16 + lrow) * DIM + quad * 32);

    v8i bf[2][4];
    #pragma unroll
    for (int tj = 0; tj < 4; ++tj) {      // prefetch B for k=0
        ((v4i*)&bf[0][tj])[0] = bptr[tj][0];
        ((v4i*)&bf[0][tj])[1] = bptr[tj][1];
    }

    // Two BK=256 A-chunks. Stage: wave rows [w*32,w*32+32), 8 instrs x 4 rows;
    // lane l: row base+(l>>4), LDS chunk p=l&15 holds global chunk p^(row&7).
    #pragma unroll
    for (int c = 0; c < 2; ++c) {
        if (c) __syncthreads();           // chunk0 ds_reads done
        #pragma unroll
        for (int h = 0; h < 8; ++h) {
            int base = wave * 32 + h * 4;
            int rowg = base + (lane >> 4);
            int g    = (lane & 15) ^ (rowg & 7);
            async_copy16(E + (size_t)(i0 + rowg) * DIM + c * 256 + g * 16,
                         As + (size_t)base * 256);
        }
        __syncthreads();                  // vmcnt drain: chunk ready

        #pragma unroll
        for (int k2 = 0; k2 < 2; ++k2) {
            const int k   = c * 2 + k2;
            const int cur = k & 1, nxt = cur ^ 1;
            v8i af[4];
            #pragma unroll
            for (int ti = 0; ti < 4; ++ti) {
                int r  = i_w + ti * 16 + lrow;
                const v4i* rp = (const v4i*)(As + (size_t)r * 256);
                int sw = r & 7;
                ((v4i*)&af[ti])[0] = rp[(k2 * 8 + quad * 2) ^ sw];
                ((v4i*)&af[ti])[1] = rp[(k2 * 8 + quad * 2 + 1) ^ sw];
            }
            if (k < 3) {                  // prefetch next k's B
                #pragma unroll
                for (int tj = 0; tj < 4; ++tj) {
                    ((v4i*)&bf[nxt][tj])[0] = bptr[tj][(k + 1) * 8];
                    ((v4i*)&bf[nxt][tj])[1] = bptr[tj][(k + 1) * 8 + 1];
                }
            }
            #pragma unroll
            for (int ti = 0; ti < 4; ++ti)
                #pragma unroll
                for (int tj = 0; tj < 4; ++tj)
                    acc[ti][tj] =
                        __builtin_amdgcn_mfma_scale_f32_16x16x128_f8f6f4(
                            af[ti], bf[cur][tj], acc[ti][tj],
                            0, 0,                 // fp8 e4m3 / e4m3
                            0, 0x7F7F7F7F,        // A scale = 1.0
                            0, 0x7F7F7F7F);       // B scale = 1.0
        }
    }
    __syncthreads();      // As dead -> reduction buffers writable

    // Epilogue. C/D: col = lane&15, row = quad*4 + reg. acc = 16*S.
    float psC[4] = {0.f, 0.f, 0.f, 0.f};
    float nsC[4] = {0.f, 0.f, 0.f, 0.f};
    #pragma unroll
    for (int ti = 0; ti < 4; ++ti) {
        #pragma unroll
        for (int reg = 0; reg < 4; ++reg) {
            int irow = i_w + ti * 16 + quad * 4 + reg;
            int li   = labI[irow];
            int gi   = i0 + irow;
            float ps = 0.f, ns = 0.f;
            #pragma unroll
            for (int tj = 0; tj < 4; ++tj) {
                int jcol = j_w + tj * 16 + lrow;
                int lj   = labJ[jcol];
                int gj   = j0 + jcol;
                float w  = __expf(fmaf(acc[ti][tj][reg], 0.0625f, -1.0f));
                bool same = (li == lj);
                float wp = (same && (gi != gj)) ? w : 0.f;
                float wn = same ? 0.f : w;
                ps += wp;  ns += wn;
                psC[tj] += wp;  nsC[tj] += wn;
            }
            rowBuf[(size_t)(vR * 128 + irow) * 17 + lrow] = (float2){ps, ns};
        }
    }
    #pragma unroll
    for (int tj = 0; tj < 4; ++tj) {
        int jcol = j_w + tj * 16 + lrow;
        colBuf[(size_t)(vC * 128 + jcol) * 5 + quad] = (float2){psC[tj], nsC[tj]};
    }
    __syncthreads();

    if (tid < 128) {
        const float2* a = rowBuf + (size_t)tid * 17;
        const float2* b = rowBuf + (size_t)(128 + tid) * 17;
        float sp = 0.f, sn = 0.f;
        #pragma unroll
        for (int u = 0; u < 16; ++u) {
            sp += a[u].x + b[u].x;
            sn += a[u].y + b[u].y;
        }
        P[(size_t)bj * BN + i0 + tid] = sp;
        N[(size_t)bj * BN + i0 + tid] = sn;
    } else if (!diag) {
        int c2 = tid - 128;
        const float2* a = colBuf + (size_t)c2 * 5;
        const float2* b = colBuf + (size_t)(128 + c2) * 5;
        float sp = 0.f, sn = 0.f;
        #pragma unroll
        for (int u = 0; u < 4; ++u) {
            sp += a[u].x + b[u].x;
            sn += a[u].y + b[u].y;
        }
        P[(size_t)bi * BN + j0 + c2] = sp;
        N[(size_t)bi * BN + j0 + c2] = sn;
    }
}

// Fused tail: 32 blocks x 256. Per-block LDS histogram, per-row partial
// reduce + loss, one atomicAdd of the pre-scaled block sum into out[0].
__global__ __launch_bounds__(256) void reduce_finalize_kernel(
        const int* __restrict__ labels, const float* __restrict__ P,
        const float* __restrict__ N, float* __restrict__ out) {
    __shared__ int cnt[128];
    __shared__ float wsum[4];
    int tid = threadIdx.x;
    if (tid < 128) cnt[tid] = 0;
    __syncthreads();
    for (int i = tid; i < BN; i += 256) atomicAdd(&cnt[labels[i]], 1);
    __syncthreads();

    int i = blockIdx.x * 256 + tid;
    float p = 0.f, n = 0.f;
    #pragma unroll 8
    for (int c = 0; c < NB; ++c) {
        p += P[(size_t)c * BN + i];
        n += N[(size_t)c * BN + i];
    }
    int   cl = cnt[labels[i]];
    float pm = p / fmaxf((float)(cl - 1), 1.0f);
    float nm = n / fmaxf((float)(BN - cl), 1.0f);
    float v  = ((cl - 1 > 0) && (BN - cl > 0))
                   ? -logf(pm / (pm + nm + EPSF)) : 0.0f;
    v *= (1.0f / (float)BN);
    #pragma unroll
    for (int m = 1; m < 64; m <<= 1) v += __shfl_xor(v, m, 64);
    if ((tid & 63) == 0) wsum[tid >> 6] = v;
    __syncthreads();
    if (tid == 0)
        atomicAdd(out, wsum[0] + wsum[1] + wsum[2] + wsum[3]);
}

extern "C" void kernel_launch(void* const* d_in, const int* in_sizes, int n_in,
                              void* d_out, int out_size, void* d_ws, size_t ws_size,
                              hipStream_t stream) {
    const float* emb   = (const float*)d_in[0];
    const int* labels  = (const int*)d_in[1];
    float* out         = (float*)d_out;

    // ws layout: E (8 MB reserved; fp8 uses 4) | P (2 MB) | N (2 MB)
    unsigned char* E   = (unsigned char*)d_ws;
    float* P           = (float*)((char*)d_ws + (size_t)BN * DIM * 2);
    float* N           = P + (size_t)NB * BN;

    normalize_kernel<<<BN / 4, 256, 0, stream>>>(emb, E, out);
    gemm_epi_kernel<<<NTILES, 256, 0, stream>>>(E, labels, P, N);
    reduce_finalize_kernel<<<32, 256, 0, stream>>>(labels, P, N, out);
}